// Round 1
// baseline (316.463 us; speedup 1.0000x reference)
//
#include <hip/hip_runtime.h>
#include <cstdint>

typedef float  f32x4  __attribute__((ext_vector_type(4)));
typedef short  short8 __attribute__((ext_vector_type(8)));
typedef _Float16 half4 __attribute__((ext_vector_type(4)));

// ---------- helpers ----------
__device__ __forceinline__ unsigned short f2bf(float f) {
    unsigned u = __builtin_bit_cast(unsigned, f);
    u += 0x7FFFu + ((u >> 16) & 1u);   // RNE
    return (unsigned short)(u >> 16);
}

// ---------- kernel 1: weights fp32 -> bf16 (3 x 256 x 256) ----------
__global__ void wconv_kernel(const float* __restrict__ wq,
                             const float* __restrict__ wk,
                             const float* __restrict__ wv,
                             unsigned short* __restrict__ Wb) {
    int p = blockIdx.x >> 8;                       // 0..2
    int i = ((blockIdx.x & 255) << 8) + threadIdx.x; // 0..65535
    const float* src = (p == 0) ? wq : ((p == 1) ? wk : wv);
    Wb[(p << 16) + i] = f2bf(src[i]);
}

// ---------- kernel 2: build X0 [B][S][256] bf16 ----------
// channels 0..223 from x (transposed), 224..255 positional encoding
__global__ void build_x0_kernel(const float* __restrict__ x,
                                unsigned short* __restrict__ X0) {
    __shared__ float tile[32][33];
    int b  = blockIdx.z;
    int ct = blockIdx.y;     // 0..7  (32 channels each)
    int st = blockIdx.x;     // 0..31 (32 s each)
    int tid = threadIdx.x;
    int lo = tid & 31, hi = tid >> 5;   // 8 rows per pass

    if (ct < 7) {
        #pragma unroll
        for (int r = 0; r < 4; ++r) {
            int c = hi + 8 * r;
            tile[c][lo] = x[((b * 224 + ct * 32 + c) << 10) + st * 32 + lo];
        }
        __syncthreads();
        #pragma unroll
        for (int r = 0; r < 4; ++r) {
            int s_loc = hi + 8 * r;
            X0[(((b << 10) + st * 32 + s_loc) << 8) + ct * 32 + lo] = f2bf(tile[lo][s_loc]);
        }
    } else {
        #pragma unroll
        for (int r = 0; r < 4; ++r) {
            int s_loc = hi + 8 * r;
            int s = st * 32 + s_loc;
            int h = s >> 5, w = s & 31;
            int ch = lo;  // 0..31 -> pe channel
            int i = (ch < 16) ? (ch * 32 + h) : ((ch - 16) * 32 + w);
            int l = i >> 4, e = i & 15;
            float val = 0.f;
            if (l > 0) {
                float ang = (float)l * powf(10000.f, -(float)(e >> 1) * 0.125f);
                val = (e & 1) ? cosf(ang) : sinf(ang);
            }
            X0[(((b << 10) + s) << 8) + 224 + ch] = f2bf(val);
        }
    }
}

// ---------- kernel 3: QKV projection ----------
// Out_T[s][o] = relu( sum_c X0[s][c] * W[o][c] + bias[o] )
// Q,K stored [B][S][256] bf16 ; V stored [B][256][S] f16
__global__ __launch_bounds__(256) void proj_kernel(
        const unsigned short* __restrict__ X0,
        const unsigned short* __restrict__ Wb,
        const float* __restrict__ bq, const float* __restrict__ bk,
        const float* __restrict__ bv,
        unsigned short* __restrict__ Q, unsigned short* __restrict__ K,
        _Float16* __restrict__ V) {
    int pb = blockIdx.z; int proj = pb >> 5; int b = pb & 31;
    int tid = threadIdx.x; int w = tid >> 6; int l = tid & 63;
    int g = l >> 4, c = l & 15;
    int s0 = blockIdx.x * 64 + w * 16;
    int o0 = blockIdx.y * 64;
    const unsigned short* Wp = Wb + (proj << 16);
    const float* bias = (proj == 0) ? bq : ((proj == 1) ? bk : bv);

    f32x4 acc[4];
    #pragma unroll
    for (int ot = 0; ot < 4; ++ot) acc[ot] = (f32x4){0.f, 0.f, 0.f, 0.f};

    const short8* arow = (const short8*)&X0[(((b << 10) + s0 + c) << 8)];
    #pragma unroll
    for (int kk = 0; kk < 8; ++kk) {
        short8 a = arow[kk * 4 + g];     // d = kk*32 + 8g .. +7
        #pragma unroll
        for (int ot = 0; ot < 4; ++ot) {
            short8 bfr = *(const short8*)&Wp[(o0 + ot * 16 + c) * 256 + kk * 32 + g * 8];
            acc[ot] = __builtin_amdgcn_mfma_f32_16x16x32_bf16(a, bfr, acc[ot], 0, 0, 0);
        }
    }

    #pragma unroll
    for (int ot = 0; ot < 4; ++ot) {
        int o = o0 + ot * 16 + c;
        float bb = bias[o];
        if (proj < 2) {
            unsigned short* dst = (proj == 0) ? Q : K;
            #pragma unroll
            for (int r = 0; r < 4; ++r) {
                float v = fmaxf(acc[ot][r] + bb, 0.f);
                int s = s0 + 4 * g + r;
                dst[(((b << 10) + s) << 8) + o] = f2bf(v);
            }
        } else {
            half4 hv;
            #pragma unroll
            for (int r = 0; r < 4; ++r)
                hv[r] = (_Float16)fmaxf(acc[ot][r] + bb, 0.f);
            *(half4*)&V[(((b << 8) + o) << 10) + s0 + 4 * g] = hv;
        }
    }
}

// ---------- kernel 4: causal attention (flash-style) ----------
// scores via swapped mfma(K_tile, Q): St[t][s]; PV via 16x16x16 f16
__global__ __launch_bounds__(256) void attn_kernel(
        const unsigned short* __restrict__ Q,
        const unsigned short* __restrict__ K,
        const _Float16* __restrict__ V,
        float* __restrict__ out) {
    int b = blockIdx.y;
    int tid = threadIdx.x; int w = tid >> 6; int l = tid & 63;
    int g = l >> 4, c = l & 15;
    int x2 = blockIdx.x;   // 0..15
    int qt = (w == 0) ? (2 * x2) : (w == 1) ? (2 * x2 + 1)
           : (w == 2) ? (63 - 2 * x2) : (62 - 2 * x2);
    int s0 = qt << 4;

    short8 qf[8];
    #pragma unroll
    for (int kk = 0; kk < 8; ++kk)
        qf[kk] = *(const short8*)&Q[(((b << 10) + s0 + c) << 8) + kk * 32 + g * 8];

    float m = -1e30f, lsum = 0.f;
    f32x4 acc[16];
    #pragma unroll
    for (int i = 0; i < 16; ++i) acc[i] = (f32x4){0.f, 0.f, 0.f, 0.f};

    for (int tt = 0; tt <= qt; ++tt) {
        int t0 = tt << 4;
        f32x4 sc = (f32x4){0.f, 0.f, 0.f, 0.f};
        #pragma unroll
        for (int kk = 0; kk < 8; ++kk) {
            short8 af = *(const short8*)&K[(((b << 10) + t0 + c) << 8) + kk * 32 + g * 8];
            sc = __builtin_amdgcn_mfma_f32_16x16x32_bf16(af, qf[kk], sc, 0, 0, 0);
        }
        float sv[4];
        #pragma unroll
        for (int r = 0; r < 4; ++r) sv[r] = sc[r] * 0.0625f;
        if (tt == qt) {   // diagonal tile: mask t > s
            #pragma unroll
            for (int r = 0; r < 4; ++r)
                if (4 * g + r > c) sv[r] = -1e30f;
        }
        float tm = fmaxf(fmaxf(sv[0], sv[1]), fmaxf(sv[2], sv[3]));
        tm = fmaxf(tm, __shfl_xor(tm, 16));
        tm = fmaxf(tm, __shfl_xor(tm, 32));
        float mnew = fmaxf(m, tm);
        float alpha = __expf(m - mnew);
        m = mnew;
        float p[4]; float ps = 0.f;
        #pragma unroll
        for (int r = 0; r < 4; ++r) { p[r] = __expf(sv[r] - m); ps += p[r]; }
        ps += __shfl_xor(ps, 16);
        ps += __shfl_xor(ps, 32);
        lsum = lsum * alpha + ps;
        #pragma unroll
        for (int i = 0; i < 16; ++i) acc[i] *= alpha;
        half4 pb;
        #pragma unroll
        for (int r = 0; r < 4; ++r) pb[r] = (_Float16)p[r];
        #pragma unroll
        for (int vt = 0; vt < 16; ++vt) {
            half4 va = *(const half4*)&V[(((b << 8) + vt * 16 + c) << 10) + t0 + 4 * g];
            acc[vt] = __builtin_amdgcn_mfma_f32_16x16x16f16(va, pb, acc[vt], 0, 0, 0);
        }
    }

    float rl = 1.f / lsum;
    #pragma unroll
    for (int vt = 0; vt < 16; ++vt) {
        #pragma unroll
        for (int r = 0; r < 4; ++r)
            out[(((b << 8) + vt * 16 + 4 * g + r) << 10) + s0 + c] = acc[vt][r] * rl;
    }
}

// ---------- launcher ----------
extern "C" void kernel_launch(void* const* d_in, const int* in_sizes, int n_in,
                              void* d_out, int out_size, void* d_ws, size_t ws_size,
                              hipStream_t stream) {
    const float* x  = (const float*)d_in[0];
    const float* wq = (const float*)d_in[1];
    const float* bq = (const float*)d_in[2];
    const float* wk = (const float*)d_in[3];
    const float* bk = (const float*)d_in[4];
    const float* wv = (const float*)d_in[5];
    const float* bv = (const float*)d_in[6];
    float* out = (float*)d_out;

    char* ws = (char*)d_ws;
    unsigned short* Wb = (unsigned short*)ws;                       // 393,216 B
    unsigned short* X0 = (unsigned short*)(ws + 393216);            // 16,777,216 B
    unsigned short* Qb = (unsigned short*)(ws + 393216 + 16777216);
    unsigned short* Kb = (unsigned short*)(ws + 393216 + 2 * 16777216);
    _Float16*       Vb = (_Float16*)     (ws + 393216 + 3 * 16777216);

    wconv_kernel<<<768, 256, 0, stream>>>(wq, wk, wv, Wb);
    build_x0_kernel<<<dim3(32, 8, 32), 256, 0, stream>>>(x, X0);
    proj_kernel<<<dim3(16, 4, 96), 256, 0, stream>>>(X0, Wb, bq, bk, bv, Qb, Kb, Vb);
    attn_kernel<<<dim3(16, 32), 256, 0, stream>>>(Qb, Kb, Vb, out);
}